// Round 7
// baseline (504.312 us; speedup 1.0000x reference)
//
#include <hip/hip_runtime.h>
#include <cstdint>
#include <cstddef>

typedef __bf16  bf16x8 __attribute__((ext_vector_type(8)));
typedef float   f32x4  __attribute__((ext_vector_type(4)));
typedef unsigned short u16x8 __attribute__((ext_vector_type(8)));
typedef unsigned short u16x4 __attribute__((ext_vector_type(4)));

#define B_SZ  4096
#define SEQ   9
#define CDIM  768
#define HEADS 12
#define DH    64
#define MROWS (B_SZ*SEQ)      // 36864
#define NQKV  (3*CDIM)        // 2304
#define NPAIR (B_SZ*HEADS)    // 49152
#define PPB   28
#define GK    768             // K for both GEMMs
#define NTK   12              // K-tiles for 256^2 kernel (GK/64)
#define NT2   24              // K-tiles for 256x128 kernel (GK/32)

#define AS1 __attribute__((address_space(1)))
#define AS3 __attribute__((address_space(3)))

__device__ inline float b2f(unsigned short u){
  union{unsigned i; float f;} x; x.i = ((unsigned)u)<<16; return x.f;
}
__device__ inline unsigned short f2b(float f){ // RNE fp32->bf16
  unsigned x = __float_as_uint(f);
  return (unsigned short)((x + 0x7fffu + ((x>>16)&1u)) >> 16);
}

// ======= fused prep: x->bf16, Wq^T, Wp^T, cos/sin table, 1 launch =======
#define CONV_BLKS (MROWS*CDIM/1024)          // 27648
#define TCQ_BLKS  (CDIM*NQKV/256)            // 6912
#define TCP_BLKS  (CDIM*CDIM/256)            // 2304
#define PREP_BLKS (CONV_BLKS+TCQ_BLKS+TCP_BLKS+3)  // 36867

__global__ __launch_bounds__(256) void k_prep(const float* __restrict__ x,
                                              unsigned short* __restrict__ xb,
                                              const float* __restrict__ Wq,
                                              unsigned short* __restrict__ Wq_t,
                                              const float* __restrict__ Wp,
                                              unsigned short* __restrict__ Wp_t,
                                              float* __restrict__ cs,
                                              float* __restrict__ sn){
  int blk = blockIdx.x, tid = threadIdx.x;
  if (blk < CONV_BLKS){
    int t = blk*256 + tid;
    float4 v = ((const float4*)x)[t];
    u16x4 o; o.x=f2b(v.x); o.y=f2b(v.y); o.z=f2b(v.z); o.w=f2b(v.w);
    ((u16x4*)xb)[t] = o;
  } else if (blk < CONV_BLKS+TCQ_BLKS){
    int t = (blk-CONV_BLKS)*256 + tid;       // output-linear [NQKV][CDIM]
    int c = t / CDIM, r = t - c*CDIM;
    Wq_t[t] = f2b(Wq[(size_t)r*NQKV + c]);
  } else if (blk < CONV_BLKS+TCQ_BLKS+TCP_BLKS){
    int t = (blk-CONV_BLKS-TCQ_BLKS)*256 + tid;  // [CDIM][CDIM]
    int c = t / CDIM, r = t - c*CDIM;
    Wp_t[t] = f2b(Wp[(size_t)r*CDIM + c]);
  } else {
    int t = (blk-CONV_BLKS-TCQ_BLKS-TCP_BLKS)*256 + tid;
    if (t < SEQ*DH){
      const float blo[9] = {1.f,4.f,8.f,10.f,12.f,30.f,1.f,8.f,1.f};
      const float bhi[9] = {4.f,8.f,10.f,12.f,30.f,45.f,8.f,30.f,45.f};
      int n = t / DH, d = t - n*DH;
      int f = (d < 32) ? (d>>1) : ((d-32)>>1);
      float freq = 3.14159265358979f * (1.0f + (4.0f/15.0f)*(float)f);
      float band = (d < 32) ? blo[n] : bhi[n];
      float ang = band * freq;
      cs[t] = cosf(ang);
      sn[t] = sinf(ang);
    }
  }
}

// ---- shared GEMM phase machinery ----
#define GLOAD(SRC, LDSOFF) \
  __builtin_amdgcn_global_load_lds((const AS1 void*)(SRC), \
      (AS3 void*)(smem + (LDSOFF) + (w<<10)), 16, 0, 0)

#define PHASE_MID  do{ __builtin_amdgcn_s_barrier(); \
  asm volatile("s_waitcnt lgkmcnt(0)" ::: "memory"); \
  __builtin_amdgcn_sched_barrier(0); \
  __builtin_amdgcn_s_setprio(1); }while(0)
#define PHASE_END  do{ __builtin_amdgcn_s_setprio(0); \
  __builtin_amdgcn_s_barrier(); }while(0)

// ====== GEMM1: 256x256, BK=64, 4 balanced phases per K-tile (R4 best) ======
#define RD_A(SLOT, H) do{ _Pragma("unroll") \
  for (int m=0;m<4;++m) aQ[m] = *(const bf16x8*)((SLOT) + aRd + ((H)*4+m)*1024); }while(0)
#define RD_B(SLOT) do{ _Pragma("unroll") \
  for (int n=0;n<4;++n) bR[n] = *(const bf16x8*)((SLOT) + bRd + n*1024); }while(0)
#define MFMA_Q(H) do{ _Pragma("unroll") \
  for (int m=0;m<4;++m){ _Pragma("unroll") \
    for (int n=0;n<4;++n) \
      acc[(H)*4+m][n] = __builtin_amdgcn_mfma_f32_16x16x32_bf16(aQ[m], bR[n], acc[(H)*4+m][n], 0,0,0); } }while(0)

#define TILE_BODY(T, DB) do{ \
  const char* aS0 = smem + (DB)*16384; \
  const char* aS1 = smem + ((DB)+1)*16384; \
  const char* bS0 = smem + 65536 + (DB)*16384; \
  const char* bS1 = smem + 65536 + ((DB)+1)*16384; \
  int u1=(T)+1; if(u1>NTK-1)u1=NTK-1; int u2=(T)+2; if(u2>NTK-1)u2=NTK-1; \
  size_t o1=(size_t)u1*64+32, o2a=(size_t)u2*64, o2b=o2a+32; \
  /* P1: A mi0-3 k0, B k0; stage B1(t+1) */ \
  RD_A(aS0,0); RD_B(bS0); \
  GLOAD(bSrc0+o1, 65536 + (3-(DB))*16384); \
  GLOAD(bSrc1+o1, 65536 + (3-(DB))*16384 + 8192); \
  PHASE_MID; MFMA_Q(0); PHASE_END; \
  /* P2: A mi4-7 k0; stage A0(t+2) */ \
  RD_A(aS0,1); \
  GLOAD(aSrc0+o2a, (DB)*16384); \
  GLOAD(aSrc1+o2a, (DB)*16384 + 8192); \
  PHASE_MID; MFMA_Q(1); PHASE_END; \
  /* P3: A mi0-3 k1, B k1; stage B0(t+2) */ \
  RD_A(aS1,0); RD_B(bS1); \
  GLOAD(bSrc0+o2a, 65536 + (DB)*16384); \
  GLOAD(bSrc1+o2a, 65536 + (DB)*16384 + 8192); \
  PHASE_MID; MFMA_Q(0); PHASE_END; \
  /* P4: A mi4-7 k1; stage A1(t+2); vmcnt(6) */ \
  RD_A(aS1,1); \
  GLOAD(aSrc0+o2b, ((DB)+1)*16384); \
  GLOAD(aSrc1+o2b, ((DB)+1)*16384 + 8192); \
  PHASE_MID; MFMA_Q(1); \
  __builtin_amdgcn_s_setprio(0); \
  asm volatile("s_waitcnt vmcnt(6)" ::: "memory"); \
  __builtin_amdgcn_s_barrier(); }while(0)

template<int WRITE_F32>
__global__ __launch_bounds__(512, 2) void k_gemm8p(const unsigned short* __restrict__ A,
                                                   const unsigned short* __restrict__ Bt,
                                                   void* __restrict__ Cout,
                                                   const float* __restrict__ bias,
                                                   int M, int N, int NTN, int NWG){
  __shared__ char smem[131072];   // A ring 4x16KB | B ring 4x16KB
  int wg = blockIdx.x;
  int cpx = NWG >> 3;
  int swz = (wg & 7)*cpx + (wg >> 3);          // bijective (NWG%8==0)
  int bm = swz / NTN, bn = swz - bm*NTN;
  int m0 = bm << 8, n0 = bn << 8;

  int tid = threadIdx.x;
  int w = tid >> 6, lane = tid & 63;
  int r = lane & 15, g4 = lane >> 4;
  int wr = w >> 2, wc = w & 3;

  // st_16x32 read-side: 16B-granule g4 ^= 2*row_bit3 (verified 0-conflict)
  int seg = g4 ^ (((r >> 3) & 1) << 1);
  int aRd = (wr*128 + r)*64 + seg*16;
  int bRd = (wc*64  + r)*64 + seg*16;

  // staging side (pre-swizzled global source; linear LDS dest)
  int srow = tid >> 2;
  int gsw  = (tid & 3) ^ (((tid >> 5) & 1) << 1);
  const unsigned short* aSrc0 = A  + (size_t)(m0 + srow)*GK + gsw*8;
  const unsigned short* aSrc1 = aSrc0 + (size_t)128*GK;
  const unsigned short* bSrc0 = Bt + (size_t)(n0 + srow)*GK + gsw*8;
  const unsigned short* bSrc1 = bSrc0 + (size_t)128*GK;

  const f32x4 fz = {0.f,0.f,0.f,0.f};
  f32x4 acc[8][4];
  #pragma unroll
  for (int mi=0;mi<8;++mi)
    #pragma unroll
    for (int ni=0;ni<4;++ni) acc[mi][ni] = fz;
  bf16x8 aQ[4], bR[4];

  // ---- prologue: 7 half-tiles ----
  GLOAD(aSrc0+ 0,     0); GLOAD(aSrc1+ 0,  8192);
  GLOAD(bSrc0+ 0, 65536); GLOAD(bSrc1+ 0, 65536+ 8192);
  GLOAD(aSrc0+32, 16384); GLOAD(aSrc1+32, 16384+8192);
  GLOAD(bSrc0+32, 65536+16384); GLOAD(bSrc1+32, 65536+16384+8192);
  GLOAD(aSrc0+64, 32768); GLOAD(aSrc1+64, 32768+8192);
  GLOAD(bSrc0+64, 65536+32768); GLOAD(bSrc1+64, 65536+32768+8192);
  GLOAD(aSrc0+96, 49152); GLOAD(aSrc1+96, 49152+8192);
  asm volatile("s_waitcnt vmcnt(6)" ::: "memory");
  __builtin_amdgcn_s_barrier();

  #pragma unroll 1
  for (int tt=0; tt<NTK; tt+=2){
    TILE_BODY(tt,   0);
    TILE_BODY(tt+1, 2);
  }
  asm volatile("s_waitcnt vmcnt(0)" ::: "memory");

  // ---- epilogue: C/D layout col=lane&15, row=(lane>>4)*4+q ----
  if (WRITE_F32){
    #pragma unroll
    for (int mi=0;mi<8;++mi){
      #pragma unroll
      for (int ni=0;ni<4;++ni){
        int col = n0 + wc*64 + ni*16 + r;
        float bb = bias ? bias[col] : 0.f;
        #pragma unroll
        for (int q=0;q<4;++q){
          int row = m0 + wr*128 + mi*16 + g4*4 + q;
          ((float*)Cout)[(size_t)row*N + col] = acc[mi][ni][q] + bb;
        }
      }
    }
  } else {
    // head-major qkv: idx = ((b*12+h)*9+i)*192 + which*64 + d
    #pragma unroll
    for (int mi=0;mi<8;++mi){
      #pragma unroll
      for (int q=0;q<4;++q){
        int row = m0 + wr*128 + mi*16 + g4*4 + q;
        int bb = row / 9;
        int ii = row - bb*9;
        size_t rb = (size_t)bb*HEADS;
        #pragma unroll
        for (int ni=0;ni<4;++ni){
          int col = n0 + wc*64 + ni*16 + r;
          int which = (col >= 1536) ? 2 : (col >= 768 ? 1 : 0);
          int rem = col - which*768;
          int h = rem >> 6, d = rem & 63;
          size_t idx = ((rb + h)*9 + ii)*192 + which*64 + d;
          ((unsigned short*)Cout)[idx] = f2b(acc[mi][ni][q]);
        }
      }
    }
  }
}

// ============ GEMM2: 256x128, BK=32, 3-slot ring, 2 blocks/CU ============
#define TILE2(T, SL, SP) do{ \
  const char* aS = smem + (SL)*16384; \
  const char* bS = smem + 49152 + (SL)*8192; \
  int u2=(T)+2; if(u2>NT2-1)u2=NT2-1; size_t o2=(size_t)u2*32; \
  _Pragma("unroll") for (int m=0;m<4;++m) aQ[m] = *(const bf16x8*)(aS + aRd + m*1024); \
  _Pragma("unroll") for (int n=0;n<4;++n) bR[n] = *(const bf16x8*)(bS + bRd + n*1024); \
  GLOAD(aSrc0+o2, (SP)*16384); \
  GLOAD(aSrc1+o2, (SP)*16384 + 8192); \
  GLOAD(bSrc +o2, 49152 + (SP)*8192); \
  PHASE_MID; \
  _Pragma("unroll") for (int m=0;m<4;++m){ _Pragma("unroll") for (int n=0;n<4;++n) \
    acc[m][n] = __builtin_amdgcn_mfma_f32_16x16x32_bf16(aQ[m], bR[n], acc[m][n], 0,0,0); } \
  __builtin_amdgcn_s_setprio(0); \
  asm volatile("s_waitcnt vmcnt(3)" ::: "memory"); \
  __builtin_amdgcn_s_barrier(); }while(0)

__global__ __launch_bounds__(512, 4) void k_gemm2b(const unsigned short* __restrict__ A,
                                                   const unsigned short* __restrict__ Bt,
                                                   float* __restrict__ C,
                                                   const float* __restrict__ bias,
                                                   int M, int N, int NTN, int NWG){
  __shared__ char smem[73728];   // A 3x16KB | B 3x8KB
  int wg = blockIdx.x;
  int cpx = NWG >> 3;
  int swz = (wg & 7)*cpx + (wg >> 3);
  int bm = swz / NTN, bn = swz - bm*NTN;
  int m0 = bm << 8, n0 = bn << 7;

  int tid = threadIdx.x;
  int w = tid >> 6, lane = tid & 63;
  int r = lane & 15, g4 = lane >> 4;
  int wr = w >> 1, wc = w & 1;

  int seg = g4 ^ (((r >> 3) & 1) << 1);
  int aRd = (wr*64 + r)*64 + seg*16;
  int bRd = (wc*64 + r)*64 + seg*16;

  int srow = tid >> 2;
  int gsw  = (tid & 3) ^ (((tid >> 5) & 1) << 1);
  const unsigned short* aSrc0 = A  + (size_t)(m0 + srow)*GK + gsw*8;
  const unsigned short* aSrc1 = aSrc0 + (size_t)128*GK;
  const unsigned short* bSrc  = Bt + (size_t)(n0 + srow)*GK + gsw*8;

  const f32x4 fz = {0.f,0.f,0.f,0.f};
  f32x4 acc[4][4];
  #pragma unroll
  for (int m=0;m<4;++m)
    #pragma unroll
    for (int n=0;n<4;++n) acc[m][n] = fz;
  bf16x8 aQ[4], bR[4];

  GLOAD(aSrc0+ 0, 0);     GLOAD(aSrc1+ 0, 8192);       GLOAD(bSrc+ 0, 49152);
  GLOAD(aSrc0+32, 16384); GLOAD(aSrc1+32, 16384+8192); GLOAD(bSrc+32, 49152+8192);
  asm volatile("s_waitcnt vmcnt(3)" ::: "memory");
  __builtin_amdgcn_s_barrier();

  #pragma unroll 1
  for (int tt=0; tt<NT2; tt+=3){
    TILE2(tt,   0, 2);
    TILE2(tt+1, 1, 0);
    TILE2(tt+2, 2, 1);
  }
  asm volatile("s_waitcnt vmcnt(0)" ::: "memory");

  #pragma unroll
  for (int mi=0;mi<4;++mi){
    #pragma unroll
    for (int ni=0;ni<4;++ni){
      int col = n0 + wc*64 + ni*16 + r;
      float bb = bias ? bias[col] : 0.f;
      #pragma unroll
      for (int q=0;q<4;++q){
        int row = m0 + wr*64 + mi*16 + g4*4 + q;
        C[(size_t)row*N + col] = acc[mi][ni][q] + bb;
      }
    }
  }
}

// ---------------- dRoFE + attention, head-major qkv ----------------
// Roped K staged as packed bf16 pairs: LDS 36.3KB -> 3 blocks/CU (VGPR-capped).
__global__ __launch_bounds__(256, 3) void k_attn(const unsigned short* __restrict__ qkv,
                                                 const float* __restrict__ demo,
                                                 const float* __restrict__ cs,
                                                 const float* __restrict__ sn,
                                                 unsigned short* __restrict__ out){
  __shared__ __align__(16) unsigned int kl[PPB][SEQ][36];  // 32 used + pad (144B rows)
  __shared__ float s_cs[SEQ*DH], s_sn[SEQ*DH];
  int tid = threadIdx.x;
  for (int t=tid; t<SEQ*DH; t+=256){ s_cs[t]=cs[t]; s_sn[t]=sn[t]; }

  int pr = tid / 9, i = tid - pr*9;
  int pair = blockIdx.x*PPB + pr;
  bool act = (pr < PPB) && (pair < NPAIR);
  int b = 0, h = 0; float age = 0.f, gen = 0.f;
  const unsigned short* base = qkv;
  if (act){
    b = pair / HEADS; h = pair - b*HEADS;
    age = demo[2*b]; gen = demo[2*b+1];
    base = qkv + (size_t)pair*(SEQ*192);
  }
  __syncthreads();

  float qr[64];
  if (act){
    const u16x8* qp = (const u16x8*)(base + (size_t)i*192);
    const u16x8* kp = (const u16x8*)(base + (size_t)i*192 + 64);
    #pragma unroll
    for (int t8=0;t8<8;++t8){
      u16x8 qv = qp[t8], kv = kp[t8];
      #pragma unroll
      for (int e=0;e<8;e+=2){
        int d = t8*8+e;
        float c0=s_cs[i*64+d], s0=s_sn[i*64+d];
        float c1=s_cs[i*64+d+1], s1=s_sn[i*64+d+1];
        float q0=b2f(qv[e]), q1=b2f(qv[e+1]);
        qr[d]   = age*q0*c0 - gen*q1*s0;
        qr[d+1] = age*q1*c1 + gen*q0*s1;
        float k0=b2f(kv[e]), k1=b2f(kv[e+1]);
        float kv0 = age*k0*c0 - gen*k1*s0;
        float kv1 = age*k1*c1 + gen*k0*s1;
        kl[pr][i][d>>1] = (unsigned)f2b(kv0) | ((unsigned)f2b(kv1)<<16);
      }
    }
  }
  __syncthreads();

  if (!act) return;

  float s[9]; float mx = -1e30f;
  #pragma unroll
  for (int j=0;j<9;++j){
    const uint4* kr = (const uint4*)(&kl[pr][j][0]);
    float acc = 0.f;
    #pragma unroll
    for (int q8=0;q8<8;++q8){
      uint4 kv = kr[q8];
      acc += qr[q8*8+0]*b2f((unsigned short)(kv.x&0xffffu)) + qr[q8*8+1]*b2f((unsigned short)(kv.x>>16));
      acc += qr[q8*8+2]*b2f((unsigned short)(kv.y&0xffffu)) + qr[q8*8+3]*b2f((unsigned short)(kv.y>>16));
      acc += qr[q8*8+4]*b2f((unsigned short)(kv.z&0xffffu)) + qr[q8*8+5]*b2f((unsigned short)(kv.z>>16));
      acc += qr[q8*8+6]*b2f((unsigned short)(kv.w&0xffffu)) + qr[q8*8+7]*b2f((unsigned short)(kv.w>>16));
    }
    s[j] = acc * 0.125f;
    mx = fmaxf(mx, s[j]);
  }
  float den = 0.f;
  #pragma unroll
  for (int j=0;j<9;++j){ s[j] = __expf(s[j]-mx); den += s[j]; }
  float inv = 1.f/den;

  float o[64];
  #pragma unroll
  for (int d=0;d<64;++d) o[d]=0.f;
  #pragma unroll
  for (int j=0;j<9;++j){
    float p = s[j]*inv;
    const u16x8* vp = (const u16x8*)(base + (size_t)j*192 + 128);
    #pragma unroll
    for (int t8=0;t8<8;++t8){
      u16x8 v = vp[t8];
      #pragma unroll
      for (int e=0;e<8;++e) o[t8*8+e] += p*b2f(v[e]);
    }
  }

  u16x8* op = (u16x8*)(out + (size_t)(b*SEQ+i)*CDIM + h*DH);
  #pragma unroll
  for (int t8=0;t8<8;++t8){
    u16x8 v;
    #pragma unroll
    for (int e=0;e<8;++e) v[e]=f2b(o[t8*8+e]);
    op[t8]=v;
  }
}

extern "C" void kernel_launch(void* const* d_in, const int* in_sizes, int n_in,
                              void* d_out, int out_size, void* d_ws, size_t ws_size,
                              hipStream_t stream){
  const float* x    = (const float*)d_in[0];
  const float* demo = (const float*)d_in[1];
  const float* Wq   = (const float*)d_in[2];
  const float* Wp   = (const float*)d_in[3];
  const float* bp   = (const float*)d_in[4];
  float* outp = (float*)d_out;

  char* wsb = (char*)d_ws;
  unsigned short* xb   = (unsigned short*)wsb;              // x bf16; reused as attn out
  unsigned short* Wq_t = (unsigned short*)(wsb + 56623104); // [2304][768]
  unsigned short* Wp_t = (unsigned short*)(wsb + 60162048); // [768][768]
  float* cs = (float*)(wsb + 61341696);
  float* sn = cs + SEQ*DH;
  unsigned short* qkv  = (unsigned short*)(wsb + 61346304); // head-major [49152][9][192]

  k_prep <<< PREP_BLKS, 256, 0, stream >>> (x, xb, Wq, Wq_t, Wp, Wp_t, cs, sn);

  {
    int nwg = (MROWS/256)*(NQKV/256);   // 144*9 = 1296, %8==0
    k_gemm8p<0><<< nwg, 512, 0, stream >>>
        (xb, Wq_t, qkv, nullptr, MROWS, NQKV, NQKV/256, nwg);
  }

  k_attn <<< (NPAIR + PPB - 1)/PPB, 256, 0, stream >>> (qkv, demo, cs, sn, xb);

  {
    int nwg = (MROWS/256)*(CDIM/128);   // 144*6 = 864, %8==0
    k_gemm2b<<< nwg, 512, 0, stream >>>
        (xb, Wp_t, outp, bp, MROWS, CDIM, CDIM/128, nwg);
  }
}

// Round 8
// 360.458 us; speedup vs baseline: 1.3991x; 1.3991x over previous
//
#include <hip/hip_runtime.h>
#include <cstdint>
#include <cstddef>

typedef __bf16  bf16x8 __attribute__((ext_vector_type(8)));
typedef float   f32x4  __attribute__((ext_vector_type(4)));
typedef unsigned short u16x8 __attribute__((ext_vector_type(8)));
typedef unsigned short u16x4 __attribute__((ext_vector_type(4)));

#define B_SZ  4096
#define SEQ   9
#define CDIM  768
#define HEADS 12
#define DH    64
#define MROWS (B_SZ*SEQ)      // 36864
#define NQKV  (3*CDIM)        // 2304
#define NPAIR (B_SZ*HEADS)    // 49152
#define PPB   28
#define GK    768             // K for both GEMMs
#define NTK   12              // K-tiles for 256^2 kernel (GK/64)
#define NT2   24              // K-tiles for 256x128 kernel (GK/32)

#define AS1 __attribute__((address_space(1)))
#define AS3 __attribute__((address_space(3)))

__device__ inline float b2f(unsigned short u){
  union{unsigned i; float f;} x; x.i = ((unsigned)u)<<16; return x.f;
}
__device__ inline unsigned short f2b(float f){ // RNE fp32->bf16
  unsigned x = __float_as_uint(f);
  return (unsigned short)((x + 0x7fffu + ((x>>16)&1u)) >> 16);
}

// ======= fused prep: x->bf16, Wq^T, Wp^T, cos/sin table, 1 launch =======
#define CONV_BLKS (MROWS*CDIM/1024)          // 27648
#define TCQ_BLKS  (CDIM*NQKV/256)            // 6912
#define TCP_BLKS  (CDIM*CDIM/256)            // 2304
#define PREP_BLKS (CONV_BLKS+TCQ_BLKS+TCP_BLKS+3)  // 36867

__global__ __launch_bounds__(256) void k_prep(const float* __restrict__ x,
                                              unsigned short* __restrict__ xb,
                                              const float* __restrict__ Wq,
                                              unsigned short* __restrict__ Wq_t,
                                              const float* __restrict__ Wp,
                                              unsigned short* __restrict__ Wp_t,
                                              float* __restrict__ cs,
                                              float* __restrict__ sn){
  int blk = blockIdx.x, tid = threadIdx.x;
  if (blk < CONV_BLKS){
    int t = blk*256 + tid;
    float4 v = ((const float4*)x)[t];
    u16x4 o; o.x=f2b(v.x); o.y=f2b(v.y); o.z=f2b(v.z); o.w=f2b(v.w);
    ((u16x4*)xb)[t] = o;
  } else if (blk < CONV_BLKS+TCQ_BLKS){
    int t = (blk-CONV_BLKS)*256 + tid;       // output-linear [NQKV][CDIM]
    int c = t / CDIM, r = t - c*CDIM;
    Wq_t[t] = f2b(Wq[(size_t)r*NQKV + c]);
  } else if (blk < CONV_BLKS+TCQ_BLKS+TCP_BLKS){
    int t = (blk-CONV_BLKS-TCQ_BLKS)*256 + tid;  // [CDIM][CDIM]
    int c = t / CDIM, r = t - c*CDIM;
    Wp_t[t] = f2b(Wp[(size_t)r*CDIM + c]);
  } else {
    int t = (blk-CONV_BLKS-TCQ_BLKS-TCP_BLKS)*256 + tid;
    if (t < SEQ*DH){
      const float blo[9] = {1.f,4.f,8.f,10.f,12.f,30.f,1.f,8.f,1.f};
      const float bhi[9] = {4.f,8.f,10.f,12.f,30.f,45.f,8.f,30.f,45.f};
      int n = t / DH, d = t - n*DH;
      int f = (d < 32) ? (d>>1) : ((d-32)>>1);
      float freq = 3.14159265358979f * (1.0f + (4.0f/15.0f)*(float)f);
      float band = (d < 32) ? blo[n] : bhi[n];
      float ang = band * freq;
      cs[t] = cosf(ang);
      sn[t] = sinf(ang);
    }
  }
}

// ---- shared GEMM phase machinery ----
#define GLOAD(SRC, LDSOFF) \
  __builtin_amdgcn_global_load_lds((const AS1 void*)(SRC), \
      (AS3 void*)(smem + (LDSOFF) + (w<<10)), 16, 0, 0)

#define PHASE_MID  do{ __builtin_amdgcn_s_barrier(); \
  asm volatile("s_waitcnt lgkmcnt(0)" ::: "memory"); \
  __builtin_amdgcn_sched_barrier(0); \
  __builtin_amdgcn_s_setprio(1); }while(0)
#define PHASE_END  do{ __builtin_amdgcn_s_setprio(0); \
  __builtin_amdgcn_s_barrier(); }while(0)

// ====== GEMM1: 256x256, BK=64, 4 balanced phases per K-tile (R4 best) ======
#define RD_A(SLOT, H) do{ _Pragma("unroll") \
  for (int m=0;m<4;++m) aQ[m] = *(const bf16x8*)((SLOT) + aRd + ((H)*4+m)*1024); }while(0)
#define RD_B(SLOT) do{ _Pragma("unroll") \
  for (int n=0;n<4;++n) bR[n] = *(const bf16x8*)((SLOT) + bRd + n*1024); }while(0)
#define MFMA_Q(H) do{ _Pragma("unroll") \
  for (int m=0;m<4;++m){ _Pragma("unroll") \
    for (int n=0;n<4;++n) \
      acc[(H)*4+m][n] = __builtin_amdgcn_mfma_f32_16x16x32_bf16(aQ[m], bR[n], acc[(H)*4+m][n], 0,0,0); } }while(0)

#define TILE_BODY(T, DB) do{ \
  const char* aS0 = smem + (DB)*16384; \
  const char* aS1 = smem + ((DB)+1)*16384; \
  const char* bS0 = smem + 65536 + (DB)*16384; \
  const char* bS1 = smem + 65536 + ((DB)+1)*16384; \
  int u1=(T)+1; if(u1>NTK-1)u1=NTK-1; int u2=(T)+2; if(u2>NTK-1)u2=NTK-1; \
  size_t o1=(size_t)u1*64+32, o2a=(size_t)u2*64, o2b=o2a+32; \
  /* P1: A mi0-3 k0, B k0; stage B1(t+1) */ \
  RD_A(aS0,0); RD_B(bS0); \
  GLOAD(bSrc0+o1, 65536 + (3-(DB))*16384); \
  GLOAD(bSrc1+o1, 65536 + (3-(DB))*16384 + 8192); \
  PHASE_MID; MFMA_Q(0); PHASE_END; \
  /* P2: A mi4-7 k0; stage A0(t+2) */ \
  RD_A(aS0,1); \
  GLOAD(aSrc0+o2a, (DB)*16384); \
  GLOAD(aSrc1+o2a, (DB)*16384 + 8192); \
  PHASE_MID; MFMA_Q(1); PHASE_END; \
  /* P3: A mi0-3 k1, B k1; stage B0(t+2) */ \
  RD_A(aS1,0); RD_B(bS1); \
  GLOAD(bSrc0+o2a, 65536 + (DB)*16384); \
  GLOAD(bSrc1+o2a, 65536 + (DB)*16384 + 8192); \
  PHASE_MID; MFMA_Q(0); PHASE_END; \
  /* P4: A mi4-7 k1; stage A1(t+2); vmcnt(6) */ \
  RD_A(aS1,1); \
  GLOAD(aSrc0+o2b, ((DB)+1)*16384); \
  GLOAD(aSrc1+o2b, ((DB)+1)*16384 + 8192); \
  PHASE_MID; MFMA_Q(1); \
  __builtin_amdgcn_s_setprio(0); \
  asm volatile("s_waitcnt vmcnt(6)" ::: "memory"); \
  __builtin_amdgcn_s_barrier(); }while(0)

template<int WRITE_F32>
__global__ __launch_bounds__(512, 2) void k_gemm8p(const unsigned short* __restrict__ A,
                                                   const unsigned short* __restrict__ Bt,
                                                   void* __restrict__ Cout,
                                                   const float* __restrict__ bias,
                                                   int M, int N, int NTN, int NWG){
  __shared__ char smem[131072];   // A ring 4x16KB | B ring 4x16KB
  int wg = blockIdx.x;
  int cpx = NWG >> 3;
  int swz = (wg & 7)*cpx + (wg >> 3);          // bijective (NWG%8==0)
  int bm = swz / NTN, bn = swz - bm*NTN;
  int m0 = bm << 8, n0 = bn << 8;

  int tid = threadIdx.x;
  int w = tid >> 6, lane = tid & 63;
  int r = lane & 15, g4 = lane >> 4;
  int wr = w >> 2, wc = w & 3;

  // st_16x32 read-side: 16B-granule g4 ^= 2*row_bit3 (verified 0-conflict)
  int seg = g4 ^ (((r >> 3) & 1) << 1);
  int aRd = (wr*128 + r)*64 + seg*16;
  int bRd = (wc*64  + r)*64 + seg*16;

  // staging side (pre-swizzled global source; linear LDS dest)
  int srow = tid >> 2;
  int gsw  = (tid & 3) ^ (((tid >> 5) & 1) << 1);
  const unsigned short* aSrc0 = A  + (size_t)(m0 + srow)*GK + gsw*8;
  const unsigned short* aSrc1 = aSrc0 + (size_t)128*GK;
  const unsigned short* bSrc0 = Bt + (size_t)(n0 + srow)*GK + gsw*8;
  const unsigned short* bSrc1 = bSrc0 + (size_t)128*GK;

  const f32x4 fz = {0.f,0.f,0.f,0.f};
  f32x4 acc[8][4];
  #pragma unroll
  for (int mi=0;mi<8;++mi)
    #pragma unroll
    for (int ni=0;ni<4;++ni) acc[mi][ni] = fz;
  bf16x8 aQ[4], bR[4];

  // ---- prologue: 7 half-tiles ----
  GLOAD(aSrc0+ 0,     0); GLOAD(aSrc1+ 0,  8192);
  GLOAD(bSrc0+ 0, 65536); GLOAD(bSrc1+ 0, 65536+ 8192);
  GLOAD(aSrc0+32, 16384); GLOAD(aSrc1+32, 16384+8192);
  GLOAD(bSrc0+32, 65536+16384); GLOAD(bSrc1+32, 65536+16384+8192);
  GLOAD(aSrc0+64, 32768); GLOAD(aSrc1+64, 32768+8192);
  GLOAD(bSrc0+64, 65536+32768); GLOAD(bSrc1+64, 65536+32768+8192);
  GLOAD(aSrc0+96, 49152); GLOAD(aSrc1+96, 49152+8192);
  asm volatile("s_waitcnt vmcnt(6)" ::: "memory");
  __builtin_amdgcn_s_barrier();

  #pragma unroll 1
  for (int tt=0; tt<NTK; tt+=2){
    TILE_BODY(tt,   0);
    TILE_BODY(tt+1, 2);
  }
  asm volatile("s_waitcnt vmcnt(0)" ::: "memory");

  // ---- epilogue: C/D layout col=lane&15, row=(lane>>4)*4+q ----
  if (WRITE_F32){
    #pragma unroll
    for (int mi=0;mi<8;++mi){
      #pragma unroll
      for (int ni=0;ni<4;++ni){
        int col = n0 + wc*64 + ni*16 + r;
        float bb = bias ? bias[col] : 0.f;
        #pragma unroll
        for (int q=0;q<4;++q){
          int row = m0 + wr*128 + mi*16 + g4*4 + q;
          ((float*)Cout)[(size_t)row*N + col] = acc[mi][ni][q] + bb;
        }
      }
    }
  } else {
    // head-major qkv: idx = ((b*12+h)*9+i)*192 + which*64 + d
    #pragma unroll
    for (int mi=0;mi<8;++mi){
      #pragma unroll
      for (int q=0;q<4;++q){
        int row = m0 + wr*128 + mi*16 + g4*4 + q;
        int bb = row / 9;
        int ii = row - bb*9;
        size_t rb = (size_t)bb*HEADS;
        #pragma unroll
        for (int ni=0;ni<4;++ni){
          int col = n0 + wc*64 + ni*16 + r;
          int which = (col >= 1536) ? 2 : (col >= 768 ? 1 : 0);
          int rem = col - which*768;
          int h = rem >> 6, d = rem & 63;
          size_t idx = ((rb + h)*9 + ii)*192 + which*64 + d;
          ((unsigned short*)Cout)[idx] = f2b(acc[mi][ni][q]);
        }
      }
    }
  }
}

// ============ GEMM2: 256x128, BK=32, 3-slot ring, 2 blocks/CU ============
#define TILE2(T, SL, SP) do{ \
  const char* aS = smem + (SL)*16384; \
  const char* bS = smem + 49152 + (SL)*8192; \
  int u2=(T)+2; if(u2>NT2-1)u2=NT2-1; size_t o2=(size_t)u2*32; \
  _Pragma("unroll") for (int m=0;m<4;++m) aQ[m] = *(const bf16x8*)(aS + aRd + m*1024); \
  _Pragma("unroll") for (int n=0;n<4;++n) bR[n] = *(const bf16x8*)(bS + bRd + n*1024); \
  GLOAD(aSrc0+o2, (SP)*16384); \
  GLOAD(aSrc1+o2, (SP)*16384 + 8192); \
  GLOAD(bSrc +o2, 49152 + (SP)*8192); \
  PHASE_MID; \
  _Pragma("unroll") for (int m=0;m<4;++m){ _Pragma("unroll") for (int n=0;n<4;++n) \
    acc[m][n] = __builtin_amdgcn_mfma_f32_16x16x32_bf16(aQ[m], bR[n], acc[m][n], 0,0,0); } \
  __builtin_amdgcn_s_setprio(0); \
  asm volatile("s_waitcnt vmcnt(3)" ::: "memory"); \
  __builtin_amdgcn_s_barrier(); }while(0)

__global__ __launch_bounds__(512, 4) void k_gemm2b(const unsigned short* __restrict__ A,
                                                   const unsigned short* __restrict__ Bt,
                                                   float* __restrict__ C,
                                                   const float* __restrict__ bias,
                                                   int M, int N, int NTN, int NWG){
  __shared__ char smem[73728];   // A 3x16KB | B 3x8KB
  int wg = blockIdx.x;
  int cpx = NWG >> 3;
  int swz = (wg & 7)*cpx + (wg >> 3);
  int bm = swz / NTN, bn = swz - bm*NTN;
  int m0 = bm << 8, n0 = bn << 7;

  int tid = threadIdx.x;
  int w = tid >> 6, lane = tid & 63;
  int r = lane & 15, g4 = lane >> 4;
  int wr = w >> 1, wc = w & 1;

  int seg = g4 ^ (((r >> 3) & 1) << 1);
  int aRd = (wr*64 + r)*64 + seg*16;
  int bRd = (wc*64 + r)*64 + seg*16;

  int srow = tid >> 2;
  int gsw  = (tid & 3) ^ (((tid >> 5) & 1) << 1);
  const unsigned short* aSrc0 = A  + (size_t)(m0 + srow)*GK + gsw*8;
  const unsigned short* aSrc1 = aSrc0 + (size_t)128*GK;
  const unsigned short* bSrc  = Bt + (size_t)(n0 + srow)*GK + gsw*8;

  const f32x4 fz = {0.f,0.f,0.f,0.f};
  f32x4 acc[4][4];
  #pragma unroll
  for (int m=0;m<4;++m)
    #pragma unroll
    for (int n=0;n<4;++n) acc[m][n] = fz;
  bf16x8 aQ[4], bR[4];

  GLOAD(aSrc0+ 0, 0);     GLOAD(aSrc1+ 0, 8192);       GLOAD(bSrc+ 0, 49152);
  GLOAD(aSrc0+32, 16384); GLOAD(aSrc1+32, 16384+8192); GLOAD(bSrc+32, 49152+8192);
  asm volatile("s_waitcnt vmcnt(3)" ::: "memory");
  __builtin_amdgcn_s_barrier();

  #pragma unroll 1
  for (int tt=0; tt<NT2; tt+=3){
    TILE2(tt,   0, 2);
    TILE2(tt+1, 1, 0);
    TILE2(tt+2, 2, 1);
  }
  asm volatile("s_waitcnt vmcnt(0)" ::: "memory");

  #pragma unroll
  for (int mi=0;mi<4;++mi){
    #pragma unroll
    for (int ni=0;ni<4;++ni){
      int col = n0 + wc*64 + ni*16 + r;
      float bb = bias ? bias[col] : 0.f;
      #pragma unroll
      for (int q=0;q<4;++q){
        int row = m0 + wr*64 + mi*16 + g4*4 + q;
        C[(size_t)row*N + col] = acc[mi][ni][q] + bb;
      }
    }
  }
}

// ---------------- dRoFE + attention v3: K and V both staged in LDS -------
// kv[pr][row][0..31]  = roped K, bf16 packed (u32 = 2 dims)
// kv[pr][row][32..63] = V, raw bf16 copy
// row stride 68 u32 = 272 B: per-wave broadcast reads from 8 distinct pr's
// land on 16B granules {0,16,...,112} mod 128 -> conflict-free.
__global__ __launch_bounds__(256) void k_attn(const unsigned short* __restrict__ qkv,
                                              const float* __restrict__ demo,
                                              const float* __restrict__ cs,
                                              const float* __restrict__ sn,
                                              unsigned short* __restrict__ out){
  __shared__ __align__(16) unsigned int kv[PPB][SEQ][68];
  __shared__ float s_cs[SEQ*DH], s_sn[SEQ*DH];
  int tid = threadIdx.x;
  for (int t=tid; t<SEQ*DH; t+=256){ s_cs[t]=cs[t]; s_sn[t]=sn[t]; }

  int pr = tid / 9, i = tid - pr*9;
  int pair = blockIdx.x*PPB + pr;
  bool act = (pr < PPB) && (pair < NPAIR);
  int b = 0, h = 0; float age = 0.f, gen = 0.f;
  const unsigned short* base = qkv;
  if (act){
    b = pair / HEADS; h = pair - b*HEADS;
    age = demo[2*b]; gen = demo[2*b+1];
    base = qkv + (size_t)pair*(SEQ*192);
  }
  __syncthreads();   // cs/sn ready

  float qr[64];
  if (act){
    const u16x8* qp = (const u16x8*)(base + (size_t)i*192);
    const u16x8* kp = (const u16x8*)(base + (size_t)i*192 + 64);
    const uint4* vp = (const uint4*)(base + (size_t)i*192 + 128);
    #pragma unroll
    for (int t8=0;t8<8;++t8){
      u16x8 qv = qp[t8], kw = kp[t8];
      unsigned int kp4[4];
      #pragma unroll
      for (int e=0;e<8;e+=2){
        int d = t8*8+e;
        float c0=s_cs[i*64+d], s0=s_sn[i*64+d];
        float c1=s_cs[i*64+d+1], s1=s_sn[i*64+d+1];
        float q0=b2f(qv[e]), q1=b2f(qv[e+1]);
        qr[d]   = age*q0*c0 - gen*q1*s0;
        qr[d+1] = age*q1*c1 + gen*q0*s1;
        float k0=b2f(kw[e]), k1=b2f(kw[e+1]);
        float r0 = age*k0*c0 - gen*k1*s0;
        float r1 = age*k1*c1 + gen*k0*s1;
        kp4[e>>1] = (unsigned)f2b(r0) | ((unsigned)f2b(r1)<<16);
      }
      *(uint4*)(&kv[pr][i][t8*4]) = *(const uint4*)kp4;   // roped K
      *(uint4*)(&kv[pr][i][32+t8*4]) = vp[t8];            // raw V copy
    }
  }
  __syncthreads();   // K,V staged

  if (!act) return;

  float s[9]; float mx = -1e30f;
  #pragma unroll
  for (int j=0;j<9;++j){
    const uint4* kr = (const uint4*)(&kv[pr][j][0]);
    float acc = 0.f;
    #pragma unroll
    for (int q8=0;q8<8;++q8){
      uint4 kk = kr[q8];
      acc += qr[q8*8+0]*b2f((unsigned short)(kk.x&0xffffu)) + qr[q8*8+1]*b2f((unsigned short)(kk.x>>16));
      acc += qr[q8*8+2]*b2f((unsigned short)(kk.y&0xffffu)) + qr[q8*8+3]*b2f((unsigned short)(kk.y>>16));
      acc += qr[q8*8+4]*b2f((unsigned short)(kk.z&0xffffu)) + qr[q8*8+5]*b2f((unsigned short)(kk.z>>16));
      acc += qr[q8*8+6]*b2f((unsigned short)(kk.w&0xffffu)) + qr[q8*8+7]*b2f((unsigned short)(kk.w>>16));
    }
    s[j] = acc * 0.125f;
    mx = fmaxf(mx, s[j]);
  }
  float den = 0.f;
  #pragma unroll
  for (int j=0;j<9;++j){ s[j] = __expf(s[j]-mx); den += s[j]; }
  float inv = 1.f/den;
  #pragma unroll
  for (int j=0;j<9;++j) s[j] *= inv;

  // PV in two 32-dim halves (o[32] keeps VGPR < 128)
  unsigned short* op = out + (size_t)(b*SEQ+i)*CDIM + h*DH;
  #pragma unroll
  for (int hf=0; hf<2; ++hf){
    float o[32];
    #pragma unroll
    for (int d=0;d<32;++d) o[d]=0.f;
    #pragma unroll
    for (int j=0;j<9;++j){
      float p = s[j];
      const uint4* vr = (const uint4*)(&kv[pr][j][32 + hf*16]);
      #pragma unroll
      for (int q4=0;q4<4;++q4){
        uint4 vv = vr[q4];
        o[q4*8+0] += p*b2f((unsigned short)(vv.x&0xffffu));
        o[q4*8+1] += p*b2f((unsigned short)(vv.x>>16));
        o[q4*8+2] += p*b2f((unsigned short)(vv.y&0xffffu));
        o[q4*8+3] += p*b2f((unsigned short)(vv.y>>16));
        o[q4*8+4] += p*b2f((unsigned short)(vv.z&0xffffu));
        o[q4*8+5] += p*b2f((unsigned short)(vv.z>>16));
        o[q4*8+6] += p*b2f((unsigned short)(vv.w&0xffffu));
        o[q4*8+7] += p*b2f((unsigned short)(vv.w>>16));
      }
    }
    #pragma unroll
    for (int t8=0;t8<4;++t8){
      u16x8 v;
      #pragma unroll
      for (int e=0;e<8;++e) v[e]=f2b(o[t8*8+e]);
      ((u16x8*)op)[hf*4 + t8] = v;
    }
  }
}

extern "C" void kernel_launch(void* const* d_in, const int* in_sizes, int n_in,
                              void* d_out, int out_size, void* d_ws, size_t ws_size,
                              hipStream_t stream){
  const float* x    = (const float*)d_in[0];
  const float* demo = (const float*)d_in[1];
  const float* Wq   = (const float*)d_in[2];
  const float* Wp   = (const float*)d_in[3];
  const float* bp   = (const float*)d_in[4];
  float* outp = (float*)d_out;

  char* wsb = (char*)d_ws;
  unsigned short* xb   = (unsigned short*)wsb;              // x bf16; reused as attn out
  unsigned short* Wq_t = (unsigned short*)(wsb + 56623104); // [2304][768]
  unsigned short* Wp_t = (unsigned short*)(wsb + 60162048); // [768][768]
  float* cs = (float*)(wsb + 61341696);
  float* sn = cs + SEQ*DH;
  unsigned short* qkv  = (unsigned short*)(wsb + 61346304); // head-major [49152][9][192]

  k_prep <<< PREP_BLKS, 256, 0, stream >>> (x, xb, Wq, Wq_t, Wp, Wp_t, cs, sn);

  {
    int nwg = (MROWS/256)*(NQKV/256);   // 144*9 = 1296, %8==0
    k_gemm8p<0><<< nwg, 512, 0, stream >>>
        (xb, Wq_t, qkv, nullptr, MROWS, NQKV, NQKV/256, nwg);
  }

  k_attn <<< (NPAIR + PPB - 1)/PPB, 256, 0, stream >>> (qkv, demo, cs, sn, xb);

  {
    int nwg = (MROWS/256)*(CDIM/128);   // 144*6 = 864, %8==0
    k_gemm2b<<< nwg, 512, 0, stream >>>
        (xb, Wp_t, outp, bp, MROWS, CDIM, CDIM/128, nwg);
  }
}

// Round 9
// 352.179 us; speedup vs baseline: 1.4320x; 1.0235x over previous
//
#include <hip/hip_runtime.h>
#include <cstdint>
#include <cstddef>

typedef __bf16  bf16x8 __attribute__((ext_vector_type(8)));
typedef float   f32x4  __attribute__((ext_vector_type(4)));
typedef unsigned short u16x8 __attribute__((ext_vector_type(8)));
typedef unsigned short u16x4 __attribute__((ext_vector_type(4)));

#define B_SZ  4096
#define SEQ   9
#define CDIM  768
#define HEADS 12
#define DH    64
#define MROWS (B_SZ*SEQ)      // 36864
#define NQKV  (3*CDIM)        // 2304
#define NPAIR (B_SZ*HEADS)    // 49152
#define PPB   28
#define GK    768             // K for both GEMMs
#define NTK   12              // K-tiles for 256^2 kernel (GK/64)
#define NT2   24              // K-tiles for 256x128 kernel (GK/32)

#define AS1 __attribute__((address_space(1)))
#define AS3 __attribute__((address_space(3)))

__device__ inline float b2f(unsigned short u){
  union{unsigned i; float f;} x; x.i = ((unsigned)u)<<16; return x.f;
}
__device__ inline unsigned short f2b(float f){ // RNE fp32->bf16
  unsigned x = __float_as_uint(f);
  return (unsigned short)((x + 0x7fffu + ((x>>16)&1u)) >> 16);
}

// ======= fused prep: x->bf16, LDS-tiled Wq^T, Wp^T, table — 1 launch =======
// W transposes use 64x64 fp32 LDS tiles: coalesced float4 reads of W rows,
// coalesced u16x4 writes of W^T rows (fixes 16x strided-read overfetch).
#define CONV_BLKS (MROWS*CDIM/1024)          // 27648
#define TCQ_BLKS  ((CDIM/64)*(NQKV/64))      // 12*36 = 432
#define TCP_BLKS  ((CDIM/64)*(CDIM/64))      // 12*12 = 144
#define PREP_BLKS (CONV_BLKS+TCQ_BLKS+TCP_BLKS+1)  // 28225

__device__ inline void tconv_tile(const float* __restrict__ in,
                                  unsigned short* __restrict__ out,
                                  int R, int C, int tr, int tc,
                                  float (*tl)[65], int tid){
  int r0 = tr*64, c0 = tc*64;
  int lr = tid >> 4, lc = (tid & 15)*4;
  #pragma unroll
  for (int p=0;p<4;++p){
    float4 v = *(const float4*)(&in[(size_t)(r0+lr+p*16)*C + c0+lc]);
    tl[lr+p*16][lc]=v.x; tl[lr+p*16][lc+1]=v.y; tl[lr+p*16][lc+2]=v.z; tl[lr+p*16][lc+3]=v.w;
  }
  __syncthreads();
  #pragma unroll
  for (int p=0;p<4;++p){
    int oc = lr+p*16;
    u16x4 o;
    o.x = f2b(tl[lc+0][oc]); o.y = f2b(tl[lc+1][oc]);
    o.z = f2b(tl[lc+2][oc]); o.w = f2b(tl[lc+3][oc]);
    *(u16x4*)(&out[(size_t)(c0+oc)*R + r0 + lc]) = o;
  }
}

__global__ __launch_bounds__(256) void k_prep(const float* __restrict__ x,
                                              unsigned short* __restrict__ xb,
                                              const float* __restrict__ Wq,
                                              unsigned short* __restrict__ Wq_t,
                                              const float* __restrict__ Wp,
                                              unsigned short* __restrict__ Wp_t,
                                              float* __restrict__ cs,
                                              float* __restrict__ sn){
  __shared__ float tl[64][65];
  int blk = blockIdx.x, tid = threadIdx.x;
  if (blk < CONV_BLKS){
    int t = blk*256 + tid;
    float4 v = ((const float4*)x)[t];
    u16x4 o; o.x=f2b(v.x); o.y=f2b(v.y); o.z=f2b(v.z); o.w=f2b(v.w);
    ((u16x4*)xb)[t] = o;
  } else if (blk < CONV_BLKS+TCQ_BLKS){
    int b2 = blk - CONV_BLKS;
    tconv_tile(Wq, Wq_t, CDIM, NQKV, b2/36, b2%36, tl, tid);
  } else if (blk < CONV_BLKS+TCQ_BLKS+TCP_BLKS){
    int b3 = blk - CONV_BLKS - TCQ_BLKS;
    tconv_tile(Wp, Wp_t, CDIM, CDIM, b3/12, b3%12, tl, tid);
  } else {
    for (int t=tid; t<SEQ*DH; t+=256){
      const float blo[9] = {1.f,4.f,8.f,10.f,12.f,30.f,1.f,8.f,1.f};
      const float bhi[9] = {4.f,8.f,10.f,12.f,30.f,45.f,8.f,30.f,45.f};
      int n = t / DH, d = t - n*DH;
      int f = (d < 32) ? (d>>1) : ((d-32)>>1);
      float freq = 3.14159265358979f * (1.0f + (4.0f/15.0f)*(float)f);
      float band = (d < 32) ? blo[n] : bhi[n];
      float ang = band * freq;
      cs[t] = cosf(ang);
      sn[t] = sinf(ang);
    }
  }
}

// ---- shared GEMM phase machinery ----
#define GLOAD(SRC, LDSOFF) \
  __builtin_amdgcn_global_load_lds((const AS1 void*)(SRC), \
      (AS3 void*)(smem + (LDSOFF) + (w<<10)), 16, 0, 0)

#define PHASE_MID  do{ __builtin_amdgcn_s_barrier(); \
  asm volatile("s_waitcnt lgkmcnt(0)" ::: "memory"); \
  __builtin_amdgcn_sched_barrier(0); \
  __builtin_amdgcn_s_setprio(1); }while(0)
#define PHASE_END  do{ __builtin_amdgcn_s_setprio(0); \
  __builtin_amdgcn_s_barrier(); }while(0)

// ====== GEMM1: 256x256, BK=64, 4 balanced phases per K-tile (R4 best) ======
#define RD_A(SLOT, H) do{ _Pragma("unroll") \
  for (int m=0;m<4;++m) aQ[m] = *(const bf16x8*)((SLOT) + aRd + ((H)*4+m)*1024); }while(0)
#define RD_B(SLOT) do{ _Pragma("unroll") \
  for (int n=0;n<4;++n) bR[n] = *(const bf16x8*)((SLOT) + bRd + n*1024); }while(0)
#define MFMA_Q(H) do{ _Pragma("unroll") \
  for (int m=0;m<4;++m){ _Pragma("unroll") \
    for (int n=0;n<4;++n) \
      acc[(H)*4+m][n] = __builtin_amdgcn_mfma_f32_16x16x32_bf16(aQ[m], bR[n], acc[(H)*4+m][n], 0,0,0); } }while(0)

#define TILE_BODY(T, DB) do{ \
  const char* aS0 = smem + (DB)*16384; \
  const char* aS1 = smem + ((DB)+1)*16384; \
  const char* bS0 = smem + 65536 + (DB)*16384; \
  const char* bS1 = smem + 65536 + ((DB)+1)*16384; \
  int u1=(T)+1; if(u1>NTK-1)u1=NTK-1; int u2=(T)+2; if(u2>NTK-1)u2=NTK-1; \
  size_t o1=(size_t)u1*64+32, o2a=(size_t)u2*64, o2b=o2a+32; \
  /* P1: A mi0-3 k0, B k0; stage B1(t+1) */ \
  RD_A(aS0,0); RD_B(bS0); \
  GLOAD(bSrc0+o1, 65536 + (3-(DB))*16384); \
  GLOAD(bSrc1+o1, 65536 + (3-(DB))*16384 + 8192); \
  PHASE_MID; MFMA_Q(0); PHASE_END; \
  /* P2: A mi4-7 k0; stage A0(t+2) */ \
  RD_A(aS0,1); \
  GLOAD(aSrc0+o2a, (DB)*16384); \
  GLOAD(aSrc1+o2a, (DB)*16384 + 8192); \
  PHASE_MID; MFMA_Q(1); PHASE_END; \
  /* P3: A mi0-3 k1, B k1; stage B0(t+2) */ \
  RD_A(aS1,0); RD_B(bS1); \
  GLOAD(bSrc0+o2a, 65536 + (DB)*16384); \
  GLOAD(bSrc1+o2a, 65536 + (DB)*16384 + 8192); \
  PHASE_MID; MFMA_Q(0); PHASE_END; \
  /* P4: A mi4-7 k1; stage A1(t+2); vmcnt(6) */ \
  RD_A(aS1,1); \
  GLOAD(aSrc0+o2b, ((DB)+1)*16384); \
  GLOAD(aSrc1+o2b, ((DB)+1)*16384 + 8192); \
  PHASE_MID; MFMA_Q(1); \
  __builtin_amdgcn_s_setprio(0); \
  asm volatile("s_waitcnt vmcnt(6)" ::: "memory"); \
  __builtin_amdgcn_s_barrier(); }while(0)

template<int WRITE_F32>
__global__ __launch_bounds__(512, 2) void k_gemm8p(const unsigned short* __restrict__ A,
                                                   const unsigned short* __restrict__ Bt,
                                                   void* __restrict__ Cout,
                                                   const float* __restrict__ bias,
                                                   int M, int N, int NTN, int NWG){
  __shared__ char smem[131072];   // A ring 4x16KB | B ring 4x16KB
  int wg = blockIdx.x;
  int cpx = NWG >> 3;
  int swz = (wg & 7)*cpx + (wg >> 3);          // bijective (NWG%8==0)
  int bm = swz / NTN, bn = swz - bm*NTN;
  int m0 = bm << 8, n0 = bn << 8;

  int tid = threadIdx.x;
  int w = tid >> 6, lane = tid & 63;
  int r = lane & 15, g4 = lane >> 4;
  int wr = w >> 2, wc = w & 3;

  // st_16x32 read-side: 16B-granule g4 ^= 2*row_bit3 (verified 0-conflict)
  int seg = g4 ^ (((r >> 3) & 1) << 1);
  int aRd = (wr*128 + r)*64 + seg*16;
  int bRd = (wc*64  + r)*64 + seg*16;

  // staging side (pre-swizzled global source; linear LDS dest)
  int srow = tid >> 2;
  int gsw  = (tid & 3) ^ (((tid >> 5) & 1) << 1);
  const unsigned short* aSrc0 = A  + (size_t)(m0 + srow)*GK + gsw*8;
  const unsigned short* aSrc1 = aSrc0 + (size_t)128*GK;
  const unsigned short* bSrc0 = Bt + (size_t)(n0 + srow)*GK + gsw*8;
  const unsigned short* bSrc1 = bSrc0 + (size_t)128*GK;

  const f32x4 fz = {0.f,0.f,0.f,0.f};
  f32x4 acc[8][4];
  #pragma unroll
  for (int mi=0;mi<8;++mi)
    #pragma unroll
    for (int ni=0;ni<4;++ni) acc[mi][ni] = fz;
  bf16x8 aQ[4], bR[4];

  // ---- prologue: 7 half-tiles ----
  GLOAD(aSrc0+ 0,     0); GLOAD(aSrc1+ 0,  8192);
  GLOAD(bSrc0+ 0, 65536); GLOAD(bSrc1+ 0, 65536+ 8192);
  GLOAD(aSrc0+32, 16384); GLOAD(aSrc1+32, 16384+8192);
  GLOAD(bSrc0+32, 65536+16384); GLOAD(bSrc1+32, 65536+16384+8192);
  GLOAD(aSrc0+64, 32768); GLOAD(aSrc1+64, 32768+8192);
  GLOAD(bSrc0+64, 65536+32768); GLOAD(bSrc1+64, 65536+32768+8192);
  GLOAD(aSrc0+96, 49152); GLOAD(aSrc1+96, 49152+8192);
  asm volatile("s_waitcnt vmcnt(6)" ::: "memory");
  __builtin_amdgcn_s_barrier();

  #pragma unroll 1
  for (int tt=0; tt<NTK; tt+=2){
    TILE_BODY(tt,   0);
    TILE_BODY(tt+1, 2);
  }
  asm volatile("s_waitcnt vmcnt(0)" ::: "memory");

  // ---- epilogue: C/D layout col=lane&15, row=(lane>>4)*4+q ----
  if (WRITE_F32){
    #pragma unroll
    for (int mi=0;mi<8;++mi){
      #pragma unroll
      for (int ni=0;ni<4;++ni){
        int col = n0 + wc*64 + ni*16 + r;
        float bb = bias ? bias[col] : 0.f;
        #pragma unroll
        for (int q=0;q<4;++q){
          int row = m0 + wr*128 + mi*16 + g4*4 + q;
          ((float*)Cout)[(size_t)row*N + col] = acc[mi][ni][q] + bb;
        }
      }
    }
  } else {
    // head-major qkv: idx = ((b*12+h)*9+i)*192 + which*64 + d
    #pragma unroll
    for (int mi=0;mi<8;++mi){
      #pragma unroll
      for (int q=0;q<4;++q){
        int row = m0 + wr*128 + mi*16 + g4*4 + q;
        int bb = row / 9;
        int ii = row - bb*9;
        size_t rb = (size_t)bb*HEADS;
        #pragma unroll
        for (int ni=0;ni<4;++ni){
          int col = n0 + wc*64 + ni*16 + r;
          int which = (col >= 1536) ? 2 : (col >= 768 ? 1 : 0);
          int rem = col - which*768;
          int h = rem >> 6, d = rem & 63;
          size_t idx = ((rb + h)*9 + ii)*192 + which*64 + d;
          ((unsigned short*)Cout)[idx] = f2b(acc[mi][ni][q]);
        }
      }
    }
  }
}

// ============ GEMM2: 256x128, BK=32, 3-slot ring, 2 blocks/CU ============
#define TILE2(T, SL, SP) do{ \
  const char* aS = smem + (SL)*16384; \
  const char* bS = smem + 49152 + (SL)*8192; \
  int u2=(T)+2; if(u2>NT2-1)u2=NT2-1; size_t o2=(size_t)u2*32; \
  _Pragma("unroll") for (int m=0;m<4;++m) aQ[m] = *(const bf16x8*)(aS + aRd + m*1024); \
  _Pragma("unroll") for (int n=0;n<4;++n) bR[n] = *(const bf16x8*)(bS + bRd + n*1024); \
  GLOAD(aSrc0+o2, (SP)*16384); \
  GLOAD(aSrc1+o2, (SP)*16384 + 8192); \
  GLOAD(bSrc +o2, 49152 + (SP)*8192); \
  PHASE_MID; \
  _Pragma("unroll") for (int m=0;m<4;++m){ _Pragma("unroll") for (int n=0;n<4;++n) \
    acc[m][n] = __builtin_amdgcn_mfma_f32_16x16x32_bf16(aQ[m], bR[n], acc[m][n], 0,0,0); } \
  __builtin_amdgcn_s_setprio(0); \
  asm volatile("s_waitcnt vmcnt(3)" ::: "memory"); \
  __builtin_amdgcn_s_barrier(); }while(0)

__global__ __launch_bounds__(512, 4) void k_gemm2b(const unsigned short* __restrict__ A,
                                                   const unsigned short* __restrict__ Bt,
                                                   float* __restrict__ C,
                                                   const float* __restrict__ bias,
                                                   int M, int N, int NTN, int NWG){
  __shared__ char smem[73728];   // A 3x16KB | B 3x8KB
  int wg = blockIdx.x;
  int cpx = NWG >> 3;
  int swz = (wg & 7)*cpx + (wg >> 3);
  int bm = swz / NTN, bn = swz - bm*NTN;
  int m0 = bm << 8, n0 = bn << 7;

  int tid = threadIdx.x;
  int w = tid >> 6, lane = tid & 63;
  int r = lane & 15, g4 = lane >> 4;
  int wr = w >> 1, wc = w & 1;

  int seg = g4 ^ (((r >> 3) & 1) << 1);
  int aRd = (wr*64 + r)*64 + seg*16;
  int bRd = (wc*64 + r)*64 + seg*16;

  int srow = tid >> 2;
  int gsw  = (tid & 3) ^ (((tid >> 5) & 1) << 1);
  const unsigned short* aSrc0 = A  + (size_t)(m0 + srow)*GK + gsw*8;
  const unsigned short* aSrc1 = aSrc0 + (size_t)128*GK;
  const unsigned short* bSrc  = Bt + (size_t)(n0 + srow)*GK + gsw*8;

  const f32x4 fz = {0.f,0.f,0.f,0.f};
  f32x4 acc[4][4];
  #pragma unroll
  for (int m=0;m<4;++m)
    #pragma unroll
    for (int n=0;n<4;++n) acc[m][n] = fz;
  bf16x8 aQ[4], bR[4];

  GLOAD(aSrc0+ 0, 0);     GLOAD(aSrc1+ 0, 8192);       GLOAD(bSrc+ 0, 49152);
  GLOAD(aSrc0+32, 16384); GLOAD(aSrc1+32, 16384+8192); GLOAD(bSrc+32, 49152+8192);
  asm volatile("s_waitcnt vmcnt(3)" ::: "memory");
  __builtin_amdgcn_s_barrier();

  #pragma unroll 1
  for (int tt=0; tt<NT2; tt+=3){
    TILE2(tt,   0, 2);
    TILE2(tt+1, 1, 0);
    TILE2(tt+2, 2, 1);
  }
  asm volatile("s_waitcnt vmcnt(0)" ::: "memory");

  #pragma unroll
  for (int mi=0;mi<4;++mi){
    #pragma unroll
    for (int ni=0;ni<4;++ni){
      int col = n0 + wc*64 + ni*16 + r;
      float bb = bias ? bias[col] : 0.f;
      #pragma unroll
      for (int q=0;q<4;++q){
        int row = m0 + wr*64 + mi*16 + g4*4 + q;
        C[(size_t)row*N + col] = acc[mi][ni][q] + bb;
      }
    }
  }
}

// ---------------- dRoFE + attention v3: K and V both staged in LDS -------
__global__ __launch_bounds__(256) void k_attn(const unsigned short* __restrict__ qkv,
                                              const float* __restrict__ demo,
                                              const float* __restrict__ cs,
                                              const float* __restrict__ sn,
                                              unsigned short* __restrict__ out){
  __shared__ __align__(16) unsigned int kv[PPB][SEQ][68];
  __shared__ float s_cs[SEQ*DH], s_sn[SEQ*DH];
  int tid = threadIdx.x;
  for (int t=tid; t<SEQ*DH; t+=256){ s_cs[t]=cs[t]; s_sn[t]=sn[t]; }

  int pr = tid / 9, i = tid - pr*9;
  int pair = blockIdx.x*PPB + pr;
  bool act = (pr < PPB) && (pair < NPAIR);
  int b = 0, h = 0; float age = 0.f, gen = 0.f;
  const unsigned short* base = qkv;
  if (act){
    b = pair / HEADS; h = pair - b*HEADS;
    age = demo[2*b]; gen = demo[2*b+1];
    base = qkv + (size_t)pair*(SEQ*192);
  }
  __syncthreads();   // cs/sn ready

  float qr[64];
  if (act){
    const u16x8* qp = (const u16x8*)(base + (size_t)i*192);
    const u16x8* kp = (const u16x8*)(base + (size_t)i*192 + 64);
    const uint4* vp = (const uint4*)(base + (size_t)i*192 + 128);
    #pragma unroll
    for (int t8=0;t8<8;++t8){
      u16x8 qv = qp[t8], kw = kp[t8];
      unsigned int kp4[4];
      #pragma unroll
      for (int e=0;e<8;e+=2){
        int d = t8*8+e;
        float c0=s_cs[i*64+d], s0=s_sn[i*64+d];
        float c1=s_cs[i*64+d+1], s1=s_sn[i*64+d+1];
        float q0=b2f(qv[e]), q1=b2f(qv[e+1]);
        qr[d]   = age*q0*c0 - gen*q1*s0;
        qr[d+1] = age*q1*c1 + gen*q0*s1;
        float k0=b2f(kw[e]), k1=b2f(kw[e+1]);
        float r0 = age*k0*c0 - gen*k1*s0;
        float r1 = age*k1*c1 + gen*k0*s1;
        kp4[e>>1] = (unsigned)f2b(r0) | ((unsigned)f2b(r1)<<16);
      }
      *(uint4*)(&kv[pr][i][t8*4]) = *(const uint4*)kp4;   // roped K
      *(uint4*)(&kv[pr][i][32+t8*4]) = vp[t8];            // raw V copy
    }
  }
  __syncthreads();   // K,V staged

  if (!act) return;

  float s[9]; float mx = -1e30f;
  #pragma unroll
  for (int j=0;j<9;++j){
    const uint4* kr = (const uint4*)(&kv[pr][j][0]);
    float acc = 0.f;
    #pragma unroll
    for (int q8=0;q8<8;++q8){
      uint4 kk = kr[q8];
      acc += qr[q8*8+0]*b2f((unsigned short)(kk.x&0xffffu)) + qr[q8*8+1]*b2f((unsigned short)(kk.x>>16));
      acc += qr[q8*8+2]*b2f((unsigned short)(kk.y&0xffffu)) + qr[q8*8+3]*b2f((unsigned short)(kk.y>>16));
      acc += qr[q8*8+4]*b2f((unsigned short)(kk.z&0xffffu)) + qr[q8*8+5]*b2f((unsigned short)(kk.z>>16));
      acc += qr[q8*8+6]*b2f((unsigned short)(kk.w&0xffffu)) + qr[q8*8+7]*b2f((unsigned short)(kk.w>>16));
    }
    s[j] = acc * 0.125f;
    mx = fmaxf(mx, s[j]);
  }
  float den = 0.f;
  #pragma unroll
  for (int j=0;j<9;++j){ s[j] = __expf(s[j]-mx); den += s[j]; }
  float inv = 1.f/den;
  #pragma unroll
  for (int j=0;j<9;++j) s[j] *= inv;

  // PV in two 32-dim halves (o[32] keeps VGPR < 128)
  unsigned short* op = out + (size_t)(b*SEQ+i)*CDIM + h*DH;
  #pragma unroll
  for (int hf=0; hf<2; ++hf){
    float o[32];
    #pragma unroll
    for (int d=0;d<32;++d) o[d]=0.f;
    #pragma unroll
    for (int j=0;j<9;++j){
      float p = s[j];
      const uint4* vr = (const uint4*)(&kv[pr][j][32 + hf*16]);
      #pragma unroll
      for (int q4=0;q4<4;++q4){
        uint4 vv = vr[q4];
        o[q4*8+0] += p*b2f((unsigned short)(vv.x&0xffffu));
        o[q4*8+1] += p*b2f((unsigned short)(vv.x>>16));
        o[q4*8+2] += p*b2f((unsigned short)(vv.y&0xffffu));
        o[q4*8+3] += p*b2f((unsigned short)(vv.y>>16));
        o[q4*8+4] += p*b2f((unsigned short)(vv.z&0xffffu));
        o[q4*8+5] += p*b2f((unsigned short)(vv.z>>16));
        o[q4*8+6] += p*b2f((unsigned short)(vv.w&0xffffu));
        o[q4*8+7] += p*b2f((unsigned short)(vv.w>>16));
      }
    }
    #pragma unroll
    for (int t8=0;t8<4;++t8){
      u16x8 v;
      #pragma unroll
      for (int e=0;e<8;++e) v[e]=f2b(o[t8*8+e]);
      ((u16x8*)op)[hf*4 + t8] = v;
    }
  }
}

extern "C" void kernel_launch(void* const* d_in, const int* in_sizes, int n_in,
                              void* d_out, int out_size, void* d_ws, size_t ws_size,
                              hipStream_t stream){
  const float* x    = (const float*)d_in[0];
  const float* demo = (const float*)d_in[1];
  const float* Wq   = (const float*)d_in[2];
  const float* Wp   = (const float*)d_in[3];
  const float* bp   = (const float*)d_in[4];
  float* outp = (float*)d_out;

  char* wsb = (char*)d_ws;
  unsigned short* xb   = (unsigned short*)wsb;              // x bf16; reused as attn out
  unsigned short* Wq_t = (unsigned short*)(wsb + 56623104); // [2304][768]
  unsigned short* Wp_t = (unsigned short*)(wsb + 60162048); // [768][768]
  float* cs = (float*)(wsb + 61341696);
  float* sn = cs + SEQ*DH;
  unsigned short* qkv  = (unsigned short*)(wsb + 61346304); // head-major [49152][9][192]

  k_prep <<< PREP_BLKS, 256, 0, stream >>> (x, xb, Wq, Wq_t, Wp, Wp_t, cs, sn);

  {
    int nwg = (MROWS/256)*(NQKV/256);   // 144*9 = 1296, %8==0
    k_gemm8p<0><<< nwg, 512, 0, stream >>>
        (xb, Wq_t, qkv, nullptr, MROWS, NQKV, NQKV/256, nwg);
  }

  k_attn <<< (NPAIR + PPB - 1)/PPB, 256, 0, stream >>> (qkv, demo, cs, sn, xb);

  {
    int nwg = (MROWS/256)*(CDIM/128);   // 144*6 = 864, %8==0
    k_gemm2b<<< nwg, 512, 0, stream >>>
        (xb, Wp_t, outp, bp, MROWS, CDIM, CDIM/128, nwg);
  }
}